// Round 4
// baseline (401.296 us; speedup 1.0000x reference)
//
#include <hip/hip_runtime.h>
#include <math.h>

#define EMBED   64
#define HIDDEN  256
#define SEQ     200
#define SEQP    208          // padded to 13 M-tiles of 16
#define MT      13           // M-tiles
#define KCH     4            // K=128 -> 4 chunks of 32 (0-1: h, 2-3: h*t)

typedef _Float16 f16x8 __attribute__((ext_vector_type(8)));
typedef _Float16 f16x4 __attribute__((ext_vector_type(4)));
typedef float    f32x4 __attribute__((ext_vector_type(4)));

// ---------------- ws layout ----------------
// [0   , 64K ) fragB  : attention B' f16 frag-order, k 0-63 = W0+W2, 64-127 = W3
// [64K , 128K) Dmat   : fp32 [64][256] = W1 - W2 (row-major)
// [128K, 192K) fragB2 : mlp_w1 f16 frag-order [nt][c][lane][j]
// [192K, 192K+1M) mlpin: f16 [4096][128] = [interest(64), t(64)] per row

__global__ void din_precompute(const float* __restrict__ attn_w1,
                               const float* __restrict__ mlp_w1,
                               _Float16* __restrict__ fragB,
                               float* __restrict__ Dmat,
                               _Float16* __restrict__ fragB2) {
  const int gid = blockIdx.x * 256 + threadIdx.x;   // [0, 12288)
  if (gid < 4096) {
    const int nt = gid >> 8, chunk = (gid >> 6) & 3, lane = gid & 63;
    const int n = nt * 16 + (lane & 15);
    const int kbase = chunk * 32 + (lane >> 4) * 8;
    #pragma unroll
    for (int j = 0; j < 8; ++j) {
      const int k = kbase + j;
      float v;
      if (k < 64) v = attn_w1[k * HIDDEN + n] + attn_w1[(128 + k) * HIDDEN + n];
      else        v = attn_w1[(192 + (k - 64)) * HIDDEN + n];
      fragB[gid * 8 + j] = (_Float16)v;
    }
  } else if (gid < 8192) {
    const int f = (gid - 4096) * 4;                 // 4 floats per thread
    const int k = f >> 8, n = f & 255;
    #pragma unroll
    for (int i = 0; i < 4; ++i)
      Dmat[f + i] = attn_w1[(64 + k) * HIDDEN + n + i] - attn_w1[(128 + k) * HIDDEN + n + i];
  } else {
    const int g = gid - 8192;                       // [0, 4096): mlp_w1 -> frag order
    const int nt = g >> 8, chunk = (g >> 6) & 3, lane = g & 63;
    const int n = nt * 16 + (lane & 15);
    const int kbase = chunk * 32 + (lane >> 4) * 8;
    #pragma unroll
    for (int j = 0; j < 8; ++j)
      fragB2[g * 8 + j] = (_Float16)mlp_w1[(kbase + j) * HIDDEN + n];
  }
}

// ---------------- main fused kernel: one block per batch row ----------------
__global__ __launch_bounds__(256, 5)
void din_fused_kernel(const int* __restrict__ user_hist,
                      const int* __restrict__ target_item,
                      const float* __restrict__ user_emb,
                      const float* __restrict__ item_emb,
                      const float* __restrict__ attn_b1,
                      const float* __restrict__ attn_w2,
                      const _Float16* __restrict__ fragB,
                      const float* __restrict__ Dmat,
                      _Float16* __restrict__ mlpin)
{
  // A-fragment order: Af[(mt*2+c)*64 + lane][8]; lane=(s&15)+16*((k>>3)&3), j=k&7
  __shared__ __align__(16) _Float16 Af[MT * 2 * 64 * 8];   // 26624 B
  __shared__ float  t_s[EMBED];
  __shared__ __align__(16) _Float16 t16[EMBED];
  __shared__ float  cl[HIDDEN];
  __shared__ float  lp[4][SEQP];     // phase 3: partial logits; phase 5: aliased as ip[4][64]
  __shared__ float  weights[SEQP];
  __shared__ float  red[8];
  // total: 26624+256+128+1024+3328+832+32 = 32224 B  -> 5 blocks/CU

  const int b    = blockIdx.x;
  const int tid  = threadIdx.x;
  const int lane = tid & 63;
  const int wave = tid >> 6;
  const int m    = lane & 15;
  const int quad = lane >> 4;

  // ---- phase 0: target embedding ----
  if (tid < EMBED) {
    const float v = item_emb[target_item[b] * EMBED + tid];
    t_s[tid] = v;
    t16[tid] = (_Float16)v;
  }
  __syncthreads();

  // ---- phase 1: gather h into A-fragment LDS (f16), zero pad rows 200..207 ----
  {
    const int* hist = user_hist + b * SEQ;
    #pragma unroll
    for (int it = 0; it < MT; ++it) {                      // 13*256 == 208*16
      const int idx = it * 256 + tid;
      const int s = idx >> 4, q = idx & 15;
      const int k0 = q * 4;
      const int off = (((s >> 4) * 2 + (k0 >> 5)) * 64 + (s & 15) + 16 * ((k0 >> 3) & 3)) * 8 + (k0 & 7);
      f16x4 v;
      if (s < SEQ) {
        const float4 hv = *reinterpret_cast<const float4*>(&user_emb[hist[s] * EMBED + k0]);
        v = f16x4{(_Float16)hv.x, (_Float16)hv.y, (_Float16)hv.z, (_Float16)hv.w};
      } else {
        v = f16x4{(_Float16)0.f, (_Float16)0.f, (_Float16)0.f, (_Float16)0.f};
      }
      *reinterpret_cast<f16x4*>(&Af[off]) = v;
    }
  }

  // ---- phase 2: per-column bias fold c_j = b1_j + t . D[:,j] ----
  {
    float cj = attn_b1[tid];
    #pragma unroll 8
    for (int k = 0; k < EMBED; ++k)
      cj += t_s[k] * Dmat[k * HIDDEN + tid];
    cl[tid] = cj;
  }
  __syncthreads();

  // ---- phase 3: K=128 f16 MFMA GEMM; wave w owns n-tiles 4w..4w+3, B in VGPRs ----
  f16x8 B[4][KCH];
  #pragma unroll
  for (int i = 0; i < 4; ++i)
    #pragma unroll
    for (int c = 0; c < KCH; ++c)
      B[i][c] = reinterpret_cast<const f16x8*>(fragB)[((4 * wave + i) * KCH + c) * 64 + lane];

  const f16x8 tv0 = *reinterpret_cast<const f16x8*>(&t16[quad * 8]);
  const f16x8 tv1 = *reinterpret_cast<const f16x8*>(&t16[32 + quad * 8]);

  float cw[4], w2w[4];
  #pragma unroll
  for (int i = 0; i < 4; ++i) {
    const int n = (4 * wave + i) * 16 + m;
    cw[i]  = cl[n];
    w2w[i] = attn_w2[n];
  }

  for (int mt = 0; mt < MT; ++mt) {
    const f16x8 a0 = *reinterpret_cast<const f16x8*>(&Af[((mt * 2 + 0) * 64 + lane) * 8]);
    const f16x8 a1 = *reinterpret_cast<const f16x8*>(&Af[((mt * 2 + 1) * 64 + lane) * 8]);
    const f16x8 h0 = a0 * tv0;      // (h*t) A-extension, v_pk_mul_f16
    const f16x8 h1 = a1 * tv1;
    float part[4] = {0.f, 0.f, 0.f, 0.f};
    #pragma unroll
    for (int i = 0; i < 4; ++i) {
      f32x4 acc = {cw[i], cw[i], cw[i], cw[i]};     // bias folded into C-init
      acc = __builtin_amdgcn_mfma_f32_16x16x32_f16(a0, B[i][0], acc, 0, 0, 0);
      acc = __builtin_amdgcn_mfma_f32_16x16x32_f16(a1, B[i][1], acc, 0, 0, 0);
      acc = __builtin_amdgcn_mfma_f32_16x16x32_f16(h0, B[i][2], acc, 0, 0, 0);
      acc = __builtin_amdgcn_mfma_f32_16x16x32_f16(h1, B[i][3], acc, 0, 0, 0);
      #pragma unroll
      for (int r = 0; r < 4; ++r)
        part[r] += fmaxf(acc[r], 0.0f) * w2w[i];
    }
    // reduce over the 16 column-lanes (n) within each quad group
    #pragma unroll
    for (int r = 0; r < 4; ++r) {
      float p = part[r];
      p += __shfl_xor(p, 1, 64);
      p += __shfl_xor(p, 2, 64);
      p += __shfl_xor(p, 4, 64);
      p += __shfl_xor(p, 8, 64);
      if (m == 0) {
        const int s = mt * 16 + quad * 4 + r;      // C/D: row = quad*4 + reg
        if (s < SEQ) lp[wave][s] = p;
      }
    }
  }
  __syncthreads();

  // ---- phase 4: softmax over SEQ (attn_b2 cancels) ----
  float v = -INFINITY;
  if (tid < SEQ) v = lp[0][tid] + lp[1][tid] + lp[2][tid] + lp[3][tid];
  float mx = v;
  #pragma unroll
  for (int off = 32; off; off >>= 1) mx = fmaxf(mx, __shfl_xor(mx, off, 64));
  if (lane == 0) red[wave] = mx;
  __syncthreads();
  mx = fmaxf(fmaxf(red[0], red[1]), fmaxf(red[2], red[3]));
  float e = (tid < SEQ) ? expf(v - mx) : 0.0f;
  float ssum = e;
  #pragma unroll
  for (int off = 32; off; off >>= 1) ssum += __shfl_xor(ssum, off, 64);
  if (lane == 0) red[4 + wave] = ssum;
  __syncthreads();
  const float tot = red[4] + red[5] + red[6] + red[7];
  if (tid < SEQP) weights[tid] = (tid < SEQ) ? e / tot : 0.0f;
  __syncthreads();

  // ---- phase 5: weighted interest pooling from A-fragments ----
  {
    float pk[16];
    #pragma unroll
    for (int i = 0; i < 16; ++i) pk[i] = 0.f;
    for (int mt = wave; mt < MT; mt += 4) {
      const f16x8 a0 = *reinterpret_cast<const f16x8*>(&Af[((mt * 2 + 0) * 64 + lane) * 8]);
      const f16x8 a1 = *reinterpret_cast<const f16x8*>(&Af[((mt * 2 + 1) * 64 + lane) * 8]);
      const float wt = weights[mt * 16 + m];
      #pragma unroll
      for (int j = 0; j < 8; ++j) {
        pk[j]     += wt * (float)a0[j];
        pk[8 + j] += wt * (float)a1[j];
      }
    }
    #pragma unroll
    for (int i = 0; i < 16; ++i) {
      float p = pk[i];
      p += __shfl_xor(p, 1, 64);
      p += __shfl_xor(p, 2, 64);
      p += __shfl_xor(p, 4, 64);
      p += __shfl_xor(p, 8, 64);
      pk[i] = p;
    }
    if (m == 0) {
      #pragma unroll
      for (int i = 0; i < 16; ++i) {
        const int k = (i >> 3) * 32 + quad * 8 + (i & 7);
        lp[wave][k] = pk[i];                       // lp reused as interest partials
      }
    }
  }
  __syncthreads();

  // ---- phase 5.5: emit head input row [interest(64), t(64)] as f16 ----
  if (tid < EMBED) {
    const float s4 = lp[0][tid] + lp[1][tid] + lp[2][tid] + lp[3][tid];
    mlpin[b * 128 + tid] = (_Float16)s4;
  } else if (tid < 2 * EMBED) {
    mlpin[b * 128 + tid] = t16[tid - EMBED];
  }
}

// ---------------- head kernel: [4096 x 128] @ [128 x 256] + relu.w2 + sigmoid ----------------
__global__ __launch_bounds__(256, 2)
void din_head_kernel(const _Float16* __restrict__ mlpin,
                     const _Float16* __restrict__ fragB2,
                     const float* __restrict__ mlp_b1,
                     const float* __restrict__ mlp_w2,
                     const float* __restrict__ mlp_b2,
                     float* __restrict__ out)
{
  const int tid  = threadIdx.x;
  const int lane = tid & 63;
  const int w    = tid >> 6;
  const int cn   = lane & 15;
  const int quad = lane >> 4;
  const int rowbase = blockIdx.x * 64 + w * 16;

  f16x8 A[4];
  #pragma unroll
  for (int c = 0; c < 4; ++c)
    A[c] = *reinterpret_cast<const f16x8*>(&mlpin[(rowbase + cn) * 128 + c * 32 + quad * 8]);

  float part[4] = {0.f, 0.f, 0.f, 0.f};
  #pragma unroll
  for (int nt = 0; nt < 16; ++nt) {
    const float b1v = mlp_b1[nt * 16 + cn];
    const float w2v = mlp_w2[nt * 16 + cn];
    f32x4 acc = {b1v, b1v, b1v, b1v};
    #pragma unroll
    for (int c = 0; c < 4; ++c) {
      const f16x8 Bf = reinterpret_cast<const f16x8*>(fragB2)[(nt * 4 + c) * 64 + lane];
      acc = __builtin_amdgcn_mfma_f32_16x16x32_f16(A[c], Bf, acc, 0, 0, 0);
    }
    #pragma unroll
    for (int r = 0; r < 4; ++r)
      part[r] += fmaxf(acc[r], 0.0f) * w2v;
  }
  const float b2 = mlp_b2[0];
  #pragma unroll
  for (int r = 0; r < 4; ++r) {
    float p = part[r];
    p += __shfl_xor(p, 1, 64);
    p += __shfl_xor(p, 2, 64);
    p += __shfl_xor(p, 4, 64);
    p += __shfl_xor(p, 8, 64);
    if (cn == 0)
      out[rowbase + quad * 4 + r] = 1.0f / (1.0f + expf(-(p + b2)));
  }
}

extern "C" void kernel_launch(void* const* d_in, const int* in_sizes, int n_in,
                              void* d_out, int out_size, void* d_ws, size_t ws_size,
                              hipStream_t stream) {
  const int*   user_hist   = (const int*)  d_in[0];
  const int*   target_item = (const int*)  d_in[1];
  const float* user_emb    = (const float*)d_in[2];
  const float* item_emb    = (const float*)d_in[3];
  const float* attn_w1     = (const float*)d_in[4];
  const float* attn_b1     = (const float*)d_in[5];
  const float* attn_w2     = (const float*)d_in[6];
  // d_in[7] = attn_b2: constant shift on logits -> cancels in softmax
  const float* mlp_w1      = (const float*)d_in[8];
  const float* mlp_b1      = (const float*)d_in[9];
  const float* mlp_w2      = (const float*)d_in[10];
  const float* mlp_b2      = (const float*)d_in[11];
  float* out = (float*)d_out;

  _Float16* fragB  = (_Float16*)d_ws;                        // 64 KB
  float*    Dmat   = (float*)((char*)d_ws + 65536);          // 64 KB
  _Float16* fragB2 = (_Float16*)((char*)d_ws + 131072);      // 64 KB
  _Float16* mlpin  = (_Float16*)((char*)d_ws + 196608);      // 1 MB

  din_precompute<<<48, 256, 0, stream>>>(attn_w1, mlp_w1, fragB, Dmat, fragB2);

  const int batch = in_sizes[1];
  din_fused_kernel<<<batch, 256, 0, stream>>>(
      user_hist, target_item, user_emb, item_emb,
      attn_b1, attn_w2, fragB, Dmat, mlpin);

  din_head_kernel<<<batch / 64, 256, 0, stream>>>(
      mlpin, fragB2, mlp_b1, mlp_w2, mlp_b2, out);
}

// Round 5
// 244.197 us; speedup vs baseline: 1.6433x; 1.6433x over previous
//
#include <hip/hip_runtime.h>
#include <math.h>

#define EMBED   64
#define HIDDEN  256
#define SEQ     200
#define SEQP    208          // padded to 13 M-tiles of 16
#define MT      13           // M-tiles
#define KCH     4            // K=128 -> 4 chunks of 32 (0-1: h, 2-3: h*t)

typedef _Float16 f16x8 __attribute__((ext_vector_type(8)));
typedef _Float16 f16x4 __attribute__((ext_vector_type(4)));
typedef float    f32x4 __attribute__((ext_vector_type(4)));

// ---------------- ws layout ----------------
// [0   , 64K ) fragB  : attention B' f16 frag-order, k 0-63 = W0+W2, 64-127 = W3
// [64K , 128K) Dmat   : fp32 [64][256] = W1 - W2 (row-major)
// [128K, 192K) fragB2 : mlp_w1 f16 frag-order [nt][c][lane][j]
// [192K, 192K+1M) mlpin: f16 [4096][128] = [interest(64), t(64)] per row

__global__ void din_precompute(const float* __restrict__ attn_w1,
                               const float* __restrict__ mlp_w1,
                               _Float16* __restrict__ fragB,
                               float* __restrict__ Dmat,
                               _Float16* __restrict__ fragB2) {
  const int gid = blockIdx.x * 256 + threadIdx.x;   // [0, 12288)
  if (gid < 4096) {
    const int nt = gid >> 8, chunk = (gid >> 6) & 3, lane = gid & 63;
    const int n = nt * 16 + (lane & 15);
    const int kbase = chunk * 32 + (lane >> 4) * 8;
    #pragma unroll
    for (int j = 0; j < 8; ++j) {
      const int k = kbase + j;
      float v;
      if (k < 64) v = attn_w1[k * HIDDEN + n] + attn_w1[(128 + k) * HIDDEN + n];
      else        v = attn_w1[(192 + (k - 64)) * HIDDEN + n];
      fragB[gid * 8 + j] = (_Float16)v;
    }
  } else if (gid < 8192) {
    const int f = (gid - 4096) * 4;                 // 4 floats per thread
    const int k = f >> 8, n = f & 255;
    #pragma unroll
    for (int i = 0; i < 4; ++i)
      Dmat[f + i] = attn_w1[(64 + k) * HIDDEN + n + i] - attn_w1[(128 + k) * HIDDEN + n + i];
  } else {
    const int g = gid - 8192;                       // [0, 4096): mlp_w1 -> frag order
    const int nt = g >> 8, chunk = (g >> 6) & 3, lane = g & 63;
    const int n = nt * 16 + (lane & 15);
    const int kbase = chunk * 32 + (lane >> 4) * 8;
    #pragma unroll
    for (int j = 0; j < 8; ++j)
      fragB2[g * 8 + j] = (_Float16)mlp_w1[(kbase + j) * HIDDEN + n];
  }
}

// ---------------- main fused kernel: one block per batch row ----------------
// launch_bounds(256,3): kernel needs ~128 unified V+A regs/thread (64 AGPR for the
// B fragments + ~64 VGPR working set). Bound 5 forced a 48-VGPR allocation ->
// scratch spill (WRITE_SIZE 128 KB -> 169 MB, dur 148 -> 307 us). Regs allow 4
// blocks/CU anyway; LDS (32.2 KB) allows 5, so occupancy is reg-limited at 4.
__global__ __launch_bounds__(256, 3)
void din_fused_kernel(const int* __restrict__ user_hist,
                      const int* __restrict__ target_item,
                      const float* __restrict__ user_emb,
                      const float* __restrict__ item_emb,
                      const float* __restrict__ attn_b1,
                      const float* __restrict__ attn_w2,
                      const _Float16* __restrict__ fragB,
                      const float* __restrict__ Dmat,
                      _Float16* __restrict__ mlpin)
{
  // A-fragment order: Af[(mt*2+c)*64 + lane][8]; lane=(s&15)+16*((k>>3)&3), j=k&7
  __shared__ __align__(16) _Float16 Af[MT * 2 * 64 * 8];   // 26624 B
  __shared__ float  t_s[EMBED];
  __shared__ __align__(16) _Float16 t16[EMBED];
  __shared__ float  cl[HIDDEN];
  __shared__ float  lp[4][SEQP];     // phase 3: partial logits; phase 5: aliased as ip[4][64]
  __shared__ float  weights[SEQP];
  __shared__ float  red[8];
  // total: 26624+256+128+1024+3328+832+32 = 32224 B

  const int b    = blockIdx.x;
  const int tid  = threadIdx.x;
  const int lane = tid & 63;
  const int wave = tid >> 6;
  const int m    = lane & 15;
  const int quad = lane >> 4;

  // ---- phase 0: target embedding ----
  if (tid < EMBED) {
    const float v = item_emb[target_item[b] * EMBED + tid];
    t_s[tid] = v;
    t16[tid] = (_Float16)v;
  }
  __syncthreads();

  // ---- phase 1: gather h into A-fragment LDS (f16), zero pad rows 200..207 ----
  {
    const int* hist = user_hist + b * SEQ;
    #pragma unroll
    for (int it = 0; it < MT; ++it) {                      // 13*256 == 208*16
      const int idx = it * 256 + tid;
      const int s = idx >> 4, q = idx & 15;
      const int k0 = q * 4;
      const int off = (((s >> 4) * 2 + (k0 >> 5)) * 64 + (s & 15) + 16 * ((k0 >> 3) & 3)) * 8 + (k0 & 7);
      f16x4 v;
      if (s < SEQ) {
        const float4 hv = *reinterpret_cast<const float4*>(&user_emb[hist[s] * EMBED + k0]);
        v = f16x4{(_Float16)hv.x, (_Float16)hv.y, (_Float16)hv.z, (_Float16)hv.w};
      } else {
        v = f16x4{(_Float16)0.f, (_Float16)0.f, (_Float16)0.f, (_Float16)0.f};
      }
      *reinterpret_cast<f16x4*>(&Af[off]) = v;
    }
  }

  // ---- phase 2: per-column bias fold c_j = b1_j + t . D[:,j] ----
  {
    float cj = attn_b1[tid];
    #pragma unroll 8
    for (int k = 0; k < EMBED; ++k)
      cj += t_s[k] * Dmat[k * HIDDEN + tid];
    cl[tid] = cj;
  }
  __syncthreads();

  // ---- phase 3: K=128 f16 MFMA GEMM; wave w owns n-tiles 4w..4w+3, B in regs ----
  f16x8 B[4][KCH];
  #pragma unroll
  for (int i = 0; i < 4; ++i)
    #pragma unroll
    for (int c = 0; c < KCH; ++c)
      B[i][c] = reinterpret_cast<const f16x8*>(fragB)[((4 * wave + i) * KCH + c) * 64 + lane];

  const f16x8 tv0 = *reinterpret_cast<const f16x8*>(&t16[quad * 8]);
  const f16x8 tv1 = *reinterpret_cast<const f16x8*>(&t16[32 + quad * 8]);

  float cw[4], w2w[4];
  #pragma unroll
  for (int i = 0; i < 4; ++i) {
    const int n = (4 * wave + i) * 16 + m;
    cw[i]  = cl[n];
    w2w[i] = attn_w2[n];
  }

  for (int mt = 0; mt < MT; ++mt) {
    const f16x8 a0 = *reinterpret_cast<const f16x8*>(&Af[((mt * 2 + 0) * 64 + lane) * 8]);
    const f16x8 a1 = *reinterpret_cast<const f16x8*>(&Af[((mt * 2 + 1) * 64 + lane) * 8]);
    const f16x8 h0 = a0 * tv0;      // (h*t) A-extension, v_pk_mul_f16
    const f16x8 h1 = a1 * tv1;
    float part[4] = {0.f, 0.f, 0.f, 0.f};
    #pragma unroll
    for (int i = 0; i < 4; ++i) {
      f32x4 acc = {cw[i], cw[i], cw[i], cw[i]};     // bias folded into C-init
      acc = __builtin_amdgcn_mfma_f32_16x16x32_f16(a0, B[i][0], acc, 0, 0, 0);
      acc = __builtin_amdgcn_mfma_f32_16x16x32_f16(a1, B[i][1], acc, 0, 0, 0);
      acc = __builtin_amdgcn_mfma_f32_16x16x32_f16(h0, B[i][2], acc, 0, 0, 0);
      acc = __builtin_amdgcn_mfma_f32_16x16x32_f16(h1, B[i][3], acc, 0, 0, 0);
      #pragma unroll
      for (int r = 0; r < 4; ++r)
        part[r] += fmaxf(acc[r], 0.0f) * w2w[i];
    }
    // reduce over the 16 column-lanes (n) within each quad group
    #pragma unroll
    for (int r = 0; r < 4; ++r) {
      float p = part[r];
      p += __shfl_xor(p, 1, 64);
      p += __shfl_xor(p, 2, 64);
      p += __shfl_xor(p, 4, 64);
      p += __shfl_xor(p, 8, 64);
      if (m == 0) {
        const int s = mt * 16 + quad * 4 + r;      // C/D: row = quad*4 + reg
        if (s < SEQ) lp[wave][s] = p;
      }
    }
  }
  __syncthreads();

  // ---- phase 4: softmax over SEQ (attn_b2 cancels) ----
  float v = -INFINITY;
  if (tid < SEQ) v = lp[0][tid] + lp[1][tid] + lp[2][tid] + lp[3][tid];
  float mx = v;
  #pragma unroll
  for (int off = 32; off; off >>= 1) mx = fmaxf(mx, __shfl_xor(mx, off, 64));
  if (lane == 0) red[wave] = mx;
  __syncthreads();
  mx = fmaxf(fmaxf(red[0], red[1]), fmaxf(red[2], red[3]));
  float e = (tid < SEQ) ? expf(v - mx) : 0.0f;
  float ssum = e;
  #pragma unroll
  for (int off = 32; off; off >>= 1) ssum += __shfl_xor(ssum, off, 64);
  if (lane == 0) red[4 + wave] = ssum;
  __syncthreads();
  const float tot = red[4] + red[5] + red[6] + red[7];
  if (tid < SEQP) weights[tid] = (tid < SEQ) ? e / tot : 0.0f;
  __syncthreads();

  // ---- phase 5: weighted interest pooling from A-fragments ----
  {
    float pk[16];
    #pragma unroll
    for (int i = 0; i < 16; ++i) pk[i] = 0.f;
    for (int mt = wave; mt < MT; mt += 4) {
      const f16x8 a0 = *reinterpret_cast<const f16x8*>(&Af[((mt * 2 + 0) * 64 + lane) * 8]);
      const f16x8 a1 = *reinterpret_cast<const f16x8*>(&Af[((mt * 2 + 1) * 64 + lane) * 8]);
      const float wt = weights[mt * 16 + m];
      #pragma unroll
      for (int j = 0; j < 8; ++j) {
        pk[j]     += wt * (float)a0[j];
        pk[8 + j] += wt * (float)a1[j];
      }
    }
    #pragma unroll
    for (int i = 0; i < 16; ++i) {
      float p = pk[i];
      p += __shfl_xor(p, 1, 64);
      p += __shfl_xor(p, 2, 64);
      p += __shfl_xor(p, 4, 64);
      p += __shfl_xor(p, 8, 64);
      pk[i] = p;
    }
    if (m == 0) {
      #pragma unroll
      for (int i = 0; i < 16; ++i) {
        const int k = (i >> 3) * 32 + quad * 8 + (i & 7);
        lp[wave][k] = pk[i];                       // lp reused as interest partials
      }
    }
  }
  __syncthreads();

  // ---- phase 5.5: emit head input row [interest(64), t(64)] as f16 ----
  if (tid < EMBED) {
    const float s4 = lp[0][tid] + lp[1][tid] + lp[2][tid] + lp[3][tid];
    mlpin[b * 128 + tid] = (_Float16)s4;
  } else if (tid < 2 * EMBED) {
    mlpin[b * 128 + tid] = t16[tid - EMBED];
  }
}

// ---------------- head kernel: [4096 x 128] @ [128 x 256] + relu.w2 + sigmoid ----------------
__global__ __launch_bounds__(256, 2)
void din_head_kernel(const _Float16* __restrict__ mlpin,
                     const _Float16* __restrict__ fragB2,
                     const float* __restrict__ mlp_b1,
                     const float* __restrict__ mlp_w2,
                     const float* __restrict__ mlp_b2,
                     float* __restrict__ out)
{
  const int tid  = threadIdx.x;
  const int lane = tid & 63;
  const int w    = tid >> 6;
  const int cn   = lane & 15;
  const int quad = lane >> 4;
  const int rowbase = blockIdx.x * 64 + w * 16;

  f16x8 A[4];
  #pragma unroll
  for (int c = 0; c < 4; ++c)
    A[c] = *reinterpret_cast<const f16x8*>(&mlpin[(rowbase + cn) * 128 + c * 32 + quad * 8]);

  float part[4] = {0.f, 0.f, 0.f, 0.f};
  #pragma unroll
  for (int nt = 0; nt < 16; ++nt) {
    const float b1v = mlp_b1[nt * 16 + cn];
    const float w2v = mlp_w2[nt * 16 + cn];
    f32x4 acc = {b1v, b1v, b1v, b1v};
    #pragma unroll
    for (int c = 0; c < 4; ++c) {
      const f16x8 Bf = reinterpret_cast<const f16x8*>(fragB2)[(nt * 4 + c) * 64 + lane];
      acc = __builtin_amdgcn_mfma_f32_16x16x32_f16(A[c], Bf, acc, 0, 0, 0);
    }
    #pragma unroll
    for (int r = 0; r < 4; ++r)
      part[r] += fmaxf(acc[r], 0.0f) * w2v;
  }
  const float b2 = mlp_b2[0];
  #pragma unroll
  for (int r = 0; r < 4; ++r) {
    float p = part[r];
    p += __shfl_xor(p, 1, 64);
    p += __shfl_xor(p, 2, 64);
    p += __shfl_xor(p, 4, 64);
    p += __shfl_xor(p, 8, 64);
    if (cn == 0)
      out[rowbase + quad * 4 + r] = 1.0f / (1.0f + expf(-(p + b2)));
  }
}

extern "C" void kernel_launch(void* const* d_in, const int* in_sizes, int n_in,
                              void* d_out, int out_size, void* d_ws, size_t ws_size,
                              hipStream_t stream) {
  const int*   user_hist   = (const int*)  d_in[0];
  const int*   target_item = (const int*)  d_in[1];
  const float* user_emb    = (const float*)d_in[2];
  const float* item_emb    = (const float*)d_in[3];
  const float* attn_w1     = (const float*)d_in[4];
  const float* attn_b1     = (const float*)d_in[5];
  const float* attn_w2     = (const float*)d_in[6];
  // d_in[7] = attn_b2: constant shift on logits -> cancels in softmax
  const float* mlp_w1      = (const float*)d_in[8];
  const float* mlp_b1      = (const float*)d_in[9];
  const float* mlp_w2      = (const float*)d_in[10];
  const float* mlp_b2      = (const float*)d_in[11];
  float* out = (float*)d_out;

  _Float16* fragB  = (_Float16*)d_ws;                        // 64 KB
  float*    Dmat   = (float*)((char*)d_ws + 65536);          // 64 KB
  _Float16* fragB2 = (_Float16*)((char*)d_ws + 131072);      // 64 KB
  _Float16* mlpin  = (_Float16*)((char*)d_ws + 196608);      // 1 MB

  din_precompute<<<48, 256, 0, stream>>>(attn_w1, mlp_w1, fragB, Dmat, fragB2);

  const int batch = in_sizes[1];
  din_fused_kernel<<<batch, 256, 0, stream>>>(
      user_hist, target_item, user_emb, item_emb,
      attn_b1, attn_w2, fragB, Dmat, mlpin);

  din_head_kernel<<<batch / 64, 256, 0, stream>>>(
      mlpin, fragB2, mlp_b1, mlp_w2, mlp_b2, out);
}

// Round 6
// 206.122 us; speedup vs baseline: 1.9469x; 1.1847x over previous
//
#include <hip/hip_runtime.h>
#include <math.h>

#define EMBED   64
#define HIDDEN  256
#define SEQ     200
#define SEQP    208          // padded to 13 s-tiles of 16
#define MT      13

typedef _Float16 f16x8  __attribute__((ext_vector_type(8)));
typedef _Float16 half2_t __attribute__((ext_vector_type(2)));
typedef float    f32x4  __attribute__((ext_vector_type(4)));

__device__ inline float fdot2(half2_t a, half2_t b, float c) {
  return __builtin_amdgcn_fdot2(a, b, c, false);
}

// ---------------- ws layout ----------------
// [0   , 64K ) fragB  : attention W'^T in A-frag order (n at lane&15, k chunks of 32)
//              k 0-63 = W0+W2, 64-127 = W3
// [64K , 96K ) D2f    : f16, (c*256+j)*8+kk = D[c*8+kk][j], D = W1-W2  (coalesced per-thread)
// [96K , 160K) fragB2 : mlp_w1^T in A-frag order
__global__ void din_precompute(const float* __restrict__ attn_w1,
                               const float* __restrict__ mlp_w1,
                               _Float16* __restrict__ fragB,
                               _Float16* __restrict__ D2f,
                               _Float16* __restrict__ fragB2) {
  const int gid = blockIdx.x * 256 + threadIdx.x;   // [0, 12288)
  if (gid < 4096) {
    const int nt = gid >> 8, kc = (gid >> 6) & 3, lane = gid & 63;
    const int n = nt * 16 + (lane & 15);
    const int kbase = kc * 32 + (lane >> 4) * 8;
    #pragma unroll
    for (int j = 0; j < 8; ++j) {
      const int k = kbase + j;
      float v;
      if (k < 64) v = attn_w1[k * HIDDEN + n] + attn_w1[(128 + k) * HIDDEN + n];
      else        v = attn_w1[(192 + (k - 64)) * HIDDEN + n];
      fragB[gid * 8 + j] = (_Float16)v;
    }
  } else if (gid < 8192) {
    const int f = (gid - 4096) * 4;                 // [0, 16384) step 4
    #pragma unroll
    for (int i = 0; i < 4; ++i) {
      const int idx = f + i;
      const int kk = idx & 7, t2 = idx >> 3;
      const int j = t2 & 255, c = t2 >> 8;
      const int k = c * 8 + kk;
      D2f[idx] = (_Float16)(attn_w1[(64 + k) * HIDDEN + j] - attn_w1[(128 + k) * HIDDEN + j]);
    }
  } else {
    const int g = gid - 8192;                       // mlp_w1 -> A-frag order
    const int nt = g >> 8, kc = (g >> 6) & 3, lane = g & 63;
    const int n = nt * 16 + (lane & 15);
    const int kbase = kc * 32 + (lane >> 4) * 8;
    #pragma unroll
    for (int j = 0; j < 8; ++j)
      fragB2[g * 8 + j] = (_Float16)mlp_w1[(kbase + j) * HIDDEN + n];
  }
}

// ---------------- single fused kernel: one block per batch row ----------------
// H^T orientation: D[row=n(quad*4+r)][col=s(lane&15)] = sum_k W'[k][n] * h[s][k]
// -> relu.w2 reduce over n is per-lane accumulate + 2 quad-shuffles per s-tile.
__global__ __launch_bounds__(256, 3)
void din_fused_kernel(const int* __restrict__ user_hist,
                      const int* __restrict__ target_item,
                      const float* __restrict__ user_emb,
                      const float* __restrict__ item_emb,
                      const float* __restrict__ attn_b1,
                      const float* __restrict__ attn_w2,
                      const float* __restrict__ mlp_b1,
                      const float* __restrict__ mlp_w2,
                      const float* __restrict__ mlp_b2,
                      const _Float16* __restrict__ fragB,
                      const _Float16* __restrict__ D2f,
                      const _Float16* __restrict__ fragB2,
                      float* __restrict__ out)
{
  // h in B-frag order: slot = (st*2+kc)*64 + lane; lane = (s&15) + 16*quad,
  // element j -> k = kc*32 + quad*8 + j. Written as full b128 per slot (conflict-free).
  __shared__ __align__(16) _Float16 Hf[MT * 2 * 64 * 8];   // 26624 B
  __shared__ __align__(16) _Float16 t16[EMBED];
  __shared__ float cl[HIDDEN];          // attention bias fold c_j
  __shared__ float w2s[HIDDEN];         // attn_w2 staged
  __shared__ float b1h[HIDDEN];         // mlp_b1 staged
  __shared__ float w2h[HIDDEN];         // mlp_w2 staged
  __shared__ float lp[4][SEQP];         // phase3: partial logits; phase5: interest partials
  __shared__ float weights[SEQP];
  __shared__ __align__(16) _Float16 mi16[EMBED];
  __shared__ float red[8];
  // total ~35.2 KB -> 4 blocks/CU (reg-limited similar)

  const int b    = blockIdx.x;
  const int tid  = threadIdx.x;
  const int lane = tid & 63;
  const int wave = tid >> 6;
  const int m    = lane & 15;
  const int quad = lane >> 4;

  // ---- phase 0: target embedding (f16) + stage small weight vectors ----
  if (tid < EMBED) t16[tid] = (_Float16)item_emb[target_item[b] * EMBED + tid];
  w2s[tid] = attn_w2[tid];
  b1h[tid] = mlp_b1[tid];
  w2h[tid] = mlp_w2[tid];
  __syncthreads();

  // ---- phase 1: gather h -> Hf, one ds_write_b128 per slot ----
  {
    const int* hist = user_hist + b * SEQ;
    for (int slot = tid; slot < MT * 2 * 64; slot += 256) {
      const int ln = slot & 63, kcomb = slot >> 6;      // kcomb in [0,26)
      const int st = kcomb >> 1, kc = kcomb & 1;
      const int s = st * 16 + (ln & 15);
      const int kb = kc * 32 + (ln >> 4) * 8;
      f16x8 v;
      if (s < SEQ) {
        const float4* src = reinterpret_cast<const float4*>(&user_emb[hist[s] * EMBED + kb]);
        const float4 x = src[0], y = src[1];
        v = f16x8{(_Float16)x.x, (_Float16)x.y, (_Float16)x.z, (_Float16)x.w,
                  (_Float16)y.x, (_Float16)y.y, (_Float16)y.z, (_Float16)y.w};
      } else {
        v = f16x8{(_Float16)0.f, (_Float16)0.f, (_Float16)0.f, (_Float16)0.f,
                  (_Float16)0.f, (_Float16)0.f, (_Float16)0.f, (_Float16)0.f};
      }
      *reinterpret_cast<f16x8*>(&Hf[slot * 8]) = v;
    }
  }

  // ---- phase 2: c_j = b1_j + t.(W1-W2)[:,j] via 8 coalesced f16x8 + 32 dot2 ----
  {
    float cj = attn_b1[tid];
    const f16x8* dp = reinterpret_cast<const f16x8*>(D2f);
    #pragma unroll
    for (int c = 0; c < 8; ++c) {
      const f16x8 dv = dp[c * HIDDEN + tid];
      const f16x8 tv = *reinterpret_cast<const f16x8*>(&t16[c * 8]);
      const half2_t* d2 = reinterpret_cast<const half2_t*>(&dv);
      const half2_t* t2 = reinterpret_cast<const half2_t*>(&tv);
      cj = fdot2(d2[0], t2[0], cj);
      cj = fdot2(d2[1], t2[1], cj);
      cj = fdot2(d2[2], t2[2], cj);
      cj = fdot2(d2[3], t2[3], cj);
    }
    cl[tid] = cj;
  }
  __syncthreads();

  // ---- phase 3: K=128 MFMA GEMM (H^T); wave owns n-tiles 4w..4w+3 ----
  f16x8 Aw[4][4];
  #pragma unroll
  for (int i = 0; i < 4; ++i)
    #pragma unroll
    for (int kc = 0; kc < 4; ++kc)
      Aw[i][kc] = reinterpret_cast<const f16x8*>(fragB)[((4 * wave + i) * 4 + kc) * 64 + lane];

  const f16x8 tv0 = *reinterpret_cast<const f16x8*>(&t16[quad * 8]);
  const f16x8 tv1 = *reinterpret_cast<const f16x8*>(&t16[32 + quad * 8]);

  float cn[4][4], w2n[4][4];
  #pragma unroll
  for (int i = 0; i < 4; ++i)
    #pragma unroll
    for (int r = 0; r < 4; ++r) {
      const int n = (4 * wave + i) * 16 + quad * 4 + r;
      cn[i][r]  = cl[n];
      w2n[i][r] = w2s[n];
    }

  for (int st = 0; st < MT; ++st) {
    const f16x8 bh0 = *reinterpret_cast<const f16x8*>(&Hf[((st * 2 + 0) * 64 + lane) * 8]);
    const f16x8 bh1 = *reinterpret_cast<const f16x8*>(&Hf[((st * 2 + 1) * 64 + lane) * 8]);
    const f16x8 bh2 = bh0 * tv0;        // h*t chunk (k 64-95), v_pk_mul_f16
    const f16x8 bh3 = bh1 * tv1;        // h*t chunk (k 96-127)
    float lg = 0.f;
    #pragma unroll
    for (int i = 0; i < 4; ++i) {
      f32x4 acc = {cn[i][0], cn[i][1], cn[i][2], cn[i][3]};
      acc = __builtin_amdgcn_mfma_f32_16x16x32_f16(Aw[i][0], bh0, acc, 0, 0, 0);
      acc = __builtin_amdgcn_mfma_f32_16x16x32_f16(Aw[i][1], bh1, acc, 0, 0, 0);
      acc = __builtin_amdgcn_mfma_f32_16x16x32_f16(Aw[i][2], bh2, acc, 0, 0, 0);
      acc = __builtin_amdgcn_mfma_f32_16x16x32_f16(Aw[i][3], bh3, acc, 0, 0, 0);
      #pragma unroll
      for (int r = 0; r < 4; ++r)
        lg += fmaxf(acc[r], 0.0f) * w2n[i][r];
    }
    // n lives in (i, quad, r); per-lane accumulate did i,r -> reduce over quads only
    lg += __shfl_xor(lg, 16, 64);
    lg += __shfl_xor(lg, 32, 64);
    if (lane < 16) lp[wave][st * 16 + lane] = lg;
  }
  __syncthreads();

  // ---- phase 4: softmax over SEQ (attn_b2 cancels) ----
  float v = -INFINITY;
  if (tid < SEQ) v = lp[0][tid] + lp[1][tid] + lp[2][tid] + lp[3][tid];
  float mx = v;
  #pragma unroll
  for (int off = 32; off; off >>= 1) mx = fmaxf(mx, __shfl_xor(mx, off, 64));
  if (lane == 0) red[wave] = mx;
  __syncthreads();
  mx = fmaxf(fmaxf(red[0], red[1]), fmaxf(red[2], red[3]));
  float e = (tid < SEQ) ? expf(v - mx) : 0.0f;
  float ssum = e;
  #pragma unroll
  for (int off = 32; off; off >>= 1) ssum += __shfl_xor(ssum, off, 64);
  if (lane == 0) red[4 + wave] = ssum;
  __syncthreads();
  const float tot = red[4] + red[5] + red[6] + red[7];
  if (tid < SEQP) weights[tid] = (tid < SEQ) ? e / tot : 0.0f;
  __syncthreads();

  // ---- phase 5: weighted interest pooling from Hf ----
  {
    float pk[16];
    #pragma unroll
    for (int i = 0; i < 16; ++i) pk[i] = 0.f;
    for (int st = wave; st < MT; st += 4) {
      const f16x8 bh0 = *reinterpret_cast<const f16x8*>(&Hf[((st * 2 + 0) * 64 + lane) * 8]);
      const f16x8 bh1 = *reinterpret_cast<const f16x8*>(&Hf[((st * 2 + 1) * 64 + lane) * 8]);
      const float wt = weights[st * 16 + m];
      #pragma unroll
      for (int j = 0; j < 8; ++j) {
        pk[j]     += wt * (float)bh0[j];
        pk[8 + j] += wt * (float)bh1[j];
      }
    }
    #pragma unroll
    for (int i = 0; i < 16; ++i) {
      float p = pk[i];
      p += __shfl_xor(p, 1, 64);
      p += __shfl_xor(p, 2, 64);
      p += __shfl_xor(p, 4, 64);
      p += __shfl_xor(p, 8, 64);
      pk[i] = p;
    }
    if (m == 0) {
      #pragma unroll
      for (int i = 0; i < 16; ++i) {
        const int k = (i >> 3) * 32 + quad * 8 + (i & 7);
        lp[wave][k] = pk[i];        // per-wave interest partials (sts handled by this wave)
      }
    }
  }
  __syncthreads();
  if (tid < EMBED)
    mi16[tid] = (_Float16)(lp[0][tid] + lp[1][tid] + lp[2][tid] + lp[3][tid]);
  __syncthreads();

  // ---- phase 6: prediction head, broadcast-B MFMA (all D cols identical) ----
  {
    f16x8 A2[4][4];
    #pragma unroll
    for (int i = 0; i < 4; ++i)
      #pragma unroll
      for (int kc = 0; kc < 4; ++kc)
        A2[i][kc] = reinterpret_cast<const f16x8*>(fragB2)[((4 * wave + i) * 4 + kc) * 64 + lane];
    const f16x8 mb0 = *reinterpret_cast<const f16x8*>(&mi16[quad * 8]);
    const f16x8 mb1 = *reinterpret_cast<const f16x8*>(&mi16[32 + quad * 8]);
    float z = 0.f;
    #pragma unroll
    for (int i = 0; i < 4; ++i) {
      float bb[4], ww[4];
      #pragma unroll
      for (int r = 0; r < 4; ++r) {
        const int n = (4 * wave + i) * 16 + quad * 4 + r;
        bb[r] = b1h[n];
        ww[r] = w2h[n];
      }
      f32x4 acc = {bb[0], bb[1], bb[2], bb[3]};
      acc = __builtin_amdgcn_mfma_f32_16x16x32_f16(A2[i][0], mb0, acc, 0, 0, 0);
      acc = __builtin_amdgcn_mfma_f32_16x16x32_f16(A2[i][1], mb1, acc, 0, 0, 0);
      acc = __builtin_amdgcn_mfma_f32_16x16x32_f16(A2[i][2], tv0, acc, 0, 0, 0);   // t rows
      acc = __builtin_amdgcn_mfma_f32_16x16x32_f16(A2[i][3], tv1, acc, 0, 0, 0);
      #pragma unroll
      for (int r = 0; r < 4; ++r)
        z += fmaxf(acc[r], 0.0f) * ww[r];
    }
    z += __shfl_xor(z, 16, 64);
    z += __shfl_xor(z, 32, 64);
    if (lane == 0) red[wave] = z;
  }
  __syncthreads();
  if (tid == 0) {
    const float zz = red[0] + red[1] + red[2] + red[3] + mlp_b2[0];
    out[b] = 1.0f / (1.0f + expf(-zz));
  }
}

extern "C" void kernel_launch(void* const* d_in, const int* in_sizes, int n_in,
                              void* d_out, int out_size, void* d_ws, size_t ws_size,
                              hipStream_t stream) {
  const int*   user_hist   = (const int*)  d_in[0];
  const int*   target_item = (const int*)  d_in[1];
  const float* user_emb    = (const float*)d_in[2];
  const float* item_emb    = (const float*)d_in[3];
  const float* attn_w1     = (const float*)d_in[4];
  const float* attn_b1     = (const float*)d_in[5];
  const float* attn_w2     = (const float*)d_in[6];
  // d_in[7] = attn_b2: constant shift on logits -> cancels in softmax
  const float* mlp_w1      = (const float*)d_in[8];
  const float* mlp_b1      = (const float*)d_in[9];
  const float* mlp_w2      = (const float*)d_in[10];
  const float* mlp_b2      = (const float*)d_in[11];
  float* out = (float*)d_out;

  _Float16* fragB  = (_Float16*)d_ws;                        // 64 KB
  _Float16* D2f    = (_Float16*)((char*)d_ws + 65536);       // 32 KB
  _Float16* fragB2 = (_Float16*)((char*)d_ws + 98304);       // 64 KB

  din_precompute<<<48, 256, 0, stream>>>(attn_w1, mlp_w1, fragB, D2f, fragB2);

  const int batch = in_sizes[1];
  din_fused_kernel<<<batch, 256, 0, stream>>>(
      user_hist, target_item, user_emb, item_emb,
      attn_b1, attn_w2, mlp_b1, mlp_w2, mlp_b2,
      fragB, D2f, fragB2, out);
}

// Round 7
// 183.064 us; speedup vs baseline: 2.1921x; 1.1260x over previous
//
#include <hip/hip_runtime.h>
#include <math.h>

#define EMBED   64
#define HIDDEN  256
#define SEQ     200
#define SEQP    208          // padded to 13 s-tiles of 16
#define MT      13

typedef _Float16 f16x8  __attribute__((ext_vector_type(8)));
typedef _Float16 half2_t __attribute__((ext_vector_type(2)));
typedef float    f32x4  __attribute__((ext_vector_type(4)));
typedef float    f32x2  __attribute__((ext_vector_type(2)));

__device__ inline float fdot2(half2_t a, half2_t b, float c) {
  return __builtin_amdgcn_fdot2(a, b, c, false);
}

// ---------------- ws layout ----------------
// [0  , 16K) fragB8 : fp8 A-frags of 16*(W0+W2)  [i_tile 16][kc 2][lane 64] x 8B
// [16K, 48K) fragW3 : f16 A-frags of 16*W3       [i_tile 16][kc 2][lane 64] x f16x8
// [48K, 80K) D2f    : f16 (c*256+j)*8+kk = (W1-W2)[c*8+kk][j]
// [80K,144K) fragB2 : f16 A-frags of mlp_w1      [i_tile 16][kc 4][lane 64] x f16x8
__global__ void din_precompute(const float* __restrict__ attn_w1,
                               const float* __restrict__ mlp_w1,
                               uint2* __restrict__ fragB8,
                               _Float16* __restrict__ fragW3,
                               _Float16* __restrict__ D2f,
                               _Float16* __restrict__ fragB2) {
  const int gid = blockIdx.x * 256 + threadIdx.x;   // [0, 12288)
  if (gid < 2048) {                                 // fragB8: fp8 16*(W0+W2)
    const int i = gid >> 7, rem = gid & 127, kc = rem >> 6, lane = rem & 63;
    const int n = i * 16 + (lane & 15);
    const int kb = kc * 32 + (lane >> 4) * 8;
    float v[8];
    #pragma unroll
    for (int j = 0; j < 8; ++j)
      v[j] = 16.0f * (attn_w1[(kb + j) * HIDDEN + n] + attn_w1[(128 + kb + j) * HIDDEN + n]);
    int lo = __builtin_amdgcn_cvt_pk_fp8_f32(v[0], v[1], 0, false);
    lo     = __builtin_amdgcn_cvt_pk_fp8_f32(v[2], v[3], lo, true);
    int hi = __builtin_amdgcn_cvt_pk_fp8_f32(v[4], v[5], 0, false);
    hi     = __builtin_amdgcn_cvt_pk_fp8_f32(v[6], v[7], hi, true);
    fragB8[gid] = uint2{(unsigned)lo, (unsigned)hi};
  } else if (gid < 4096) {                          // fragW3: f16 16*W3
    const int g = gid - 2048;
    const int i = g >> 7, rem = g & 127, kc = rem >> 6, lane = rem & 63;
    const int n = i * 16 + (lane & 15);
    const int kb = kc * 32 + (lane >> 4) * 8;
    #pragma unroll
    for (int j = 0; j < 8; ++j)
      fragW3[g * 8 + j] = (_Float16)(16.0f * attn_w1[(192 + kb + j) * HIDDEN + n]);
  } else if (gid < 8192) {                          // D2f
    const int f = (gid - 4096) * 4;
    #pragma unroll
    for (int i = 0; i < 4; ++i) {
      const int idx = f + i;
      const int kk = idx & 7, t2 = idx >> 3;
      const int j = t2 & 255, c = t2 >> 8;
      const int k = c * 8 + kk;
      D2f[idx] = (_Float16)(attn_w1[(64 + k) * HIDDEN + j] - attn_w1[(128 + k) * HIDDEN + j]);
    }
  } else {                                          // fragB2: mlp_w1 f16 A-frags
    const int g = gid - 8192;
    const int nt = g >> 8, kc = (g >> 6) & 3, lane = g & 63;
    const int n = nt * 16 + (lane & 15);
    const int kb = kc * 32 + (lane >> 4) * 8;
    #pragma unroll
    for (int j = 0; j < 8; ++j)
      fragB2[g * 8 + j] = (_Float16)mlp_w1[(kb + j) * HIDDEN + n];
  }
}

// ---------------- single fused kernel: one block (512 thr, 8 waves) per row ----------------
// fp8 GEMM scaling: Hf8 = fp8(16h), A-frags = fp8(16(W0+W2)) / fp8(16 t*W3)
// -> acc = 256*(pre-relu). C-init = 256*c_j; epilogue multiplies w2/256.
// launch_bounds(512,8): forces <=64 VGPR -> 8 waves/SIMD; LDS 21.6 KB -> 4+ blocks/CU.
__global__ __launch_bounds__(512, 8)
void din_fused_kernel(const int* __restrict__ user_hist,
                      const int* __restrict__ target_item,
                      const float* __restrict__ user_emb,
                      const float* __restrict__ item_emb,
                      const float* __restrict__ attn_b1,
                      const float* __restrict__ attn_w2,
                      const float* __restrict__ mlp_b1,
                      const float* __restrict__ mlp_w2,
                      const float* __restrict__ mlp_b2,
                      const uint2* __restrict__ fragB8,
                      const _Float16* __restrict__ fragW3,
                      const _Float16* __restrict__ D2f,
                      const _Float16* __restrict__ fragB2,
                      float* __restrict__ out)
{
  // Hf8[(st*2+kc)*64 + lane]: 8 fp8 bytes = 16*h[s][k], s = st*16+(lane&15),
  // k = kc*32 + (lane>>4)*8 + j  (B-frag order for mfma_f32_16x16x32_fp8_fp8)
  __shared__ __align__(16) uint2 Hf8[MT * 2 * 64];    // 13312 B
  __shared__ __align__(16) _Float16 t16[EMBED];       // 128
  __shared__ float cl[HIDDEN];                        // 1024
  __shared__ float lp[8][SEQP];                       // 6656: logits partials; later interest partials
  __shared__ float weights[SEQP];                     // 832
  __shared__ __align__(16) _Float16 mi16[EMBED];      // 128
  __shared__ float red[16];                           // 64
  // total 22144 B

  const int b    = blockIdx.x;
  const int tid  = threadIdx.x;
  const int lane = tid & 63;
  const int wave = tid >> 6;
  const int m    = lane & 15;
  const int quad = lane >> 4;

  // ---- phase 0/1: target embedding + gather h -> fp8 LDS; Aw8 frags to regs ----
  if (tid < EMBED) t16[tid] = (_Float16)item_emb[target_item[b] * EMBED + tid];

  long long Aw8[2][2];
  #pragma unroll
  for (int i = 0; i < 2; ++i)
    #pragma unroll
    for (int c = 0; c < 2; ++c)
      Aw8[i][c] = __builtin_bit_cast(long long, fragB8[((2 * wave + i) * 2 + c) * 64 + lane]);

  {
    const int* hist = user_hist + b * SEQ;
    for (int slot = tid; slot < MT * 2 * 64; slot += 512) {
      const int ln = slot & 63, kcomb = slot >> 6;
      const int st = kcomb >> 1, kc = kcomb & 1;
      const int s = st * 16 + (ln & 15);
      const int kb = kc * 32 + (ln >> 4) * 8;
      uint2 pv = uint2{0u, 0u};
      if (s < SEQ) {
        const float4* src = reinterpret_cast<const float4*>(&user_emb[hist[s] * EMBED + kb]);
        const float4 x = src[0], y = src[1];
        int lo = __builtin_amdgcn_cvt_pk_fp8_f32(16.f * x.x, 16.f * x.y, 0, false);
        lo     = __builtin_amdgcn_cvt_pk_fp8_f32(16.f * x.z, 16.f * x.w, lo, true);
        int hi = __builtin_amdgcn_cvt_pk_fp8_f32(16.f * y.x, 16.f * y.y, 0, false);
        hi     = __builtin_amdgcn_cvt_pk_fp8_f32(16.f * y.z, 16.f * y.w, hi, true);
        pv = uint2{(unsigned)lo, (unsigned)hi};
      }
      Hf8[slot] = pv;
    }
  }
  __syncthreads();

  // ---- phase 2: c_j = b1_j + t.(W1-W2)[:,j]  (threads 0-255) ----
  if (tid < HIDDEN) {
    float cj = attn_b1[tid];
    const f16x8* dp = reinterpret_cast<const f16x8*>(D2f);
    #pragma unroll
    for (int c = 0; c < 8; ++c) {
      const f16x8 dv = dp[c * HIDDEN + tid];
      const f16x8 tv = *reinterpret_cast<const f16x8*>(&t16[c * 8]);
      const half2_t* d2 = reinterpret_cast<const half2_t*>(&dv);
      const half2_t* t2 = reinterpret_cast<const half2_t*>(&tv);
      cj = fdot2(d2[0], t2[0], cj);
      cj = fdot2(d2[1], t2[1], cj);
      cj = fdot2(d2[2], t2[2], cj);
      cj = fdot2(d2[3], t2[3], cj);
    }
    cl[tid] = cj;
  }

  // ---- t-folded W3 A-frags: AwT = fp8(16*t_k*W3[k][n]) (needs t16 only) ----
  long long AwT[2][2];
  #pragma unroll
  for (int i = 0; i < 2; ++i)
    #pragma unroll
    for (int c = 0; c < 2; ++c) {
      const f16x8 w3v = reinterpret_cast<const f16x8*>(fragW3)[((2 * wave + i) * 2 + c) * 64 + lane];
      const f16x8 tw  = *reinterpret_cast<const f16x8*>(&t16[c * 32 + quad * 8]);
      const f16x8 p = w3v * tw;
      int lo = __builtin_amdgcn_cvt_pk_fp8_f32((float)p[0], (float)p[1], 0, false);
      lo     = __builtin_amdgcn_cvt_pk_fp8_f32((float)p[2], (float)p[3], lo, true);
      int hi = __builtin_amdgcn_cvt_pk_fp8_f32((float)p[4], (float)p[5], 0, false);
      hi     = __builtin_amdgcn_cvt_pk_fp8_f32((float)p[6], (float)p[7], hi, true);
      AwT[i][c] = __builtin_bit_cast(long long, uint2{(unsigned)lo, (unsigned)hi});
    }
  __syncthreads();

  // ---- phase 3: fp8 K=128 MFMA GEMM (H^T); wave owns n-tiles 2w, 2w+1 ----
  float cn[2][4], w2n[2][4];
  #pragma unroll
  for (int i = 0; i < 2; ++i)
    #pragma unroll
    for (int r = 0; r < 4; ++r) {
      const int n = (2 * wave + i) * 16 + quad * 4 + r;
      cn[i][r]  = 256.0f * cl[n];
      w2n[i][r] = attn_w2[n] * (1.0f / 256.0f);
    }

  for (int st = 0; st < MT; ++st) {
    const long long b0 = __builtin_bit_cast(long long, Hf8[(st * 2 + 0) * 64 + lane]);
    const long long b1 = __builtin_bit_cast(long long, Hf8[(st * 2 + 1) * 64 + lane]);
    float lg = 0.f;
    #pragma unroll
    for (int i = 0; i < 2; ++i) {
      f32x4 acc = {cn[i][0], cn[i][1], cn[i][2], cn[i][3]};
      acc = __builtin_amdgcn_mfma_f32_16x16x32_fp8_fp8(Aw8[i][0], b0, acc, 0, 0, 0);
      acc = __builtin_amdgcn_mfma_f32_16x16x32_fp8_fp8(Aw8[i][1], b1, acc, 0, 0, 0);
      acc = __builtin_amdgcn_mfma_f32_16x16x32_fp8_fp8(AwT[i][0], b0, acc, 0, 0, 0);
      acc = __builtin_amdgcn_mfma_f32_16x16x32_fp8_fp8(AwT[i][1], b1, acc, 0, 0, 0);
      #pragma unroll
      for (int r = 0; r < 4; ++r)
        lg += fmaxf(acc[r], 0.0f) * w2n[i][r];
    }
    lg += __shfl_xor(lg, 16, 64);
    lg += __shfl_xor(lg, 32, 64);
    if (lane < 16) lp[wave][st * 16 + lane] = lg;
  }
  __syncthreads();

  // ---- phase 4: softmax over SEQ (attn_b2 cancels) ----
  float v = -INFINITY;
  if (tid < SEQ)
    v = lp[0][tid] + lp[1][tid] + lp[2][tid] + lp[3][tid]
      + lp[4][tid] + lp[5][tid] + lp[6][tid] + lp[7][tid];
  float mx = v;
  #pragma unroll
  for (int off = 32; off; off >>= 1) mx = fmaxf(mx, __shfl_xor(mx, off, 64));
  if (lane == 0) red[wave] = mx;
  __syncthreads();
  mx = fmaxf(fmaxf(fmaxf(red[0], red[1]), fmaxf(red[2], red[3])),
             fmaxf(fmaxf(red[4], red[5]), fmaxf(red[6], red[7])));
  float e = (tid < SEQ) ? expf(v - mx) : 0.0f;
  float ssum = e;
  #pragma unroll
  for (int off = 32; off; off >>= 1) ssum += __shfl_xor(ssum, off, 64);
  if (lane == 0) red[8 + wave] = ssum;
  __syncthreads();
  const float tot = red[8] + red[9] + red[10] + red[11]
                  + red[12] + red[13] + red[14] + red[15];
  if (tid < SEQP) weights[tid] = (tid < SEQ) ? e / tot : 0.0f;
  __syncthreads();

  // ---- phase 5: weighted interest pooling; wave -> (kc = w&1, st-group = w>>1) ----
  {
    const int kc = wave & 1, g = wave >> 1;
    float pk[8];
    #pragma unroll
    for (int j = 0; j < 8; ++j) pk[j] = 0.f;
    for (int st = g; st < MT; st += 4) {
      const float wt = weights[st * 16 + m];
      const uint2 hv = Hf8[(st * 2 + kc) * 64 + lane];
      const f32x2 f0 = __builtin_amdgcn_cvt_pk_f32_fp8((int)hv.x, false);
      const f32x2 f1 = __builtin_amdgcn_cvt_pk_f32_fp8((int)hv.x, true);
      const f32x2 f2 = __builtin_amdgcn_cvt_pk_f32_fp8((int)hv.y, false);
      const f32x2 f3 = __builtin_amdgcn_cvt_pk_f32_fp8((int)hv.y, true);
      pk[0] += wt * f0.x;  pk[1] += wt * f0.y;
      pk[2] += wt * f1.x;  pk[3] += wt * f1.y;
      pk[4] += wt * f2.x;  pk[5] += wt * f2.y;
      pk[6] += wt * f3.x;  pk[7] += wt * f3.y;
    }
    #pragma unroll
    for (int j = 0; j < 8; ++j) {
      float p = pk[j];
      p += __shfl_xor(p, 1, 64);
      p += __shfl_xor(p, 2, 64);
      p += __shfl_xor(p, 4, 64);
      p += __shfl_xor(p, 8, 64);
      pk[j] = p;
    }
    if (m == 0) {
      #pragma unroll
      for (int j = 0; j < 8; ++j)
        lp[g][kc * 32 + quad * 8 + j] = pk[j];     // lp reused: interest partials
    }
  }
  __syncthreads();
  if (tid < EMBED)
    mi16[tid] = (_Float16)((lp[0][tid] + lp[1][tid] + lp[2][tid] + lp[3][tid]) * 0.0625f);
  __syncthreads();

  // ---- phase 6: prediction head, f16 MFMA, broadcast-B; A2 loaded per i (reg cap) ----
  {
    const f16x8 mb0 = *reinterpret_cast<const f16x8*>(&mi16[quad * 8]);
    const f16x8 mb1 = *reinterpret_cast<const f16x8*>(&mi16[32 + quad * 8]);
    const f16x8 tv0 = *reinterpret_cast<const f16x8*>(&t16[quad * 8]);
    const f16x8 tv1 = *reinterpret_cast<const f16x8*>(&t16[32 + quad * 8]);
    float z = 0.f;
    #pragma unroll
    for (int i = 0; i < 2; ++i) {
      const f16x8* B2 = reinterpret_cast<const f16x8*>(fragB2) + ((2 * wave + i) * 4) * 64 + lane;
      float bb[4], ww[4];
      #pragma unroll
      for (int r = 0; r < 4; ++r) {
        const int n = (2 * wave + i) * 16 + quad * 4 + r;
        bb[r] = mlp_b1[n];
        ww[r] = mlp_w2[n];
      }
      f32x4 acc = {bb[0], bb[1], bb[2], bb[3]};
      acc = __builtin_amdgcn_mfma_f32_16x16x32_f16(B2[0],       mb0, acc, 0, 0, 0);
      acc = __builtin_amdgcn_mfma_f32_16x16x32_f16(B2[64],      mb1, acc, 0, 0, 0);
      acc = __builtin_amdgcn_mfma_f32_16x16x32_f16(B2[128],     tv0, acc, 0, 0, 0);
      acc = __builtin_amdgcn_mfma_f32_16x16x32_f16(B2[192],     tv1, acc, 0, 0, 0);
      #pragma unroll
      for (int r = 0; r < 4; ++r)
        z += fmaxf(acc[r], 0.0f) * ww[r];
    }
    z += __shfl_xor(z, 16, 64);
    z += __shfl_xor(z, 32, 64);
    if (lane == 0) red[wave] = z;
  }
  __syncthreads();
  if (tid == 0) {
    const float zz = red[0] + red[1] + red[2] + red[3]
                   + red[4] + red[5] + red[6] + red[7] + mlp_b2[0];
    out[b] = 1.0f / (1.0f + expf(-zz));
  }
}

extern "C" void kernel_launch(void* const* d_in, const int* in_sizes, int n_in,
                              void* d_out, int out_size, void* d_ws, size_t ws_size,
                              hipStream_t stream) {
  const int*   user_hist   = (const int*)  d_in[0];
  const int*   target_item = (const int*)  d_in[1];
  const float* user_emb    = (const float*)d_in[2];
  const float* item_emb    = (const float*)d_in[3];
  const float* attn_w1     = (const float*)d_in[4];
  const float* attn_b1     = (const float*)d_in[5];
  const float* attn_w2     = (const float*)d_in[6];
  // d_in[7] = attn_b2: constant shift on logits -> cancels in softmax
  const float* mlp_w1      = (const float*)d_in[8];
  const float* mlp_b1      = (const float*)d_in[9];
  const float* mlp_w2      = (const float*)d_in[10];
  const float* mlp_b2      = (const float*)d_in[11];
  float* out = (float*)d_out;

  uint2*    fragB8 = (uint2*)d_ws;                           // 16 KB
  _Float16* fragW3 = (_Float16*)((char*)d_ws + 16384);       // 32 KB
  _Float16* D2f    = (_Float16*)((char*)d_ws + 49152);       // 32 KB
  _Float16* fragB2 = (_Float16*)((char*)d_ws + 81920);       // 64 KB

  din_precompute<<<48, 256, 0, stream>>>(attn_w1, mlp_w1, fragB8, fragW3, D2f, fragB2);

  const int batch = in_sizes[1];
  din_fused_kernel<<<batch, 512, 0, stream>>>(
      user_hist, target_item, user_emb, item_emb,
      attn_b1, attn_w2, mlp_b1, mlp_w2, mlp_b2,
      fragB8, fragW3, D2f, fragB2, out);
}

// Round 8
// 180.265 us; speedup vs baseline: 2.2261x; 1.0155x over previous
//
#include <hip/hip_runtime.h>
#include <math.h>

#define EMBED   64
#define HIDDEN  256
#define SEQ     200
#define SEQP    208          // padded to 13 s-tiles of 16
#define MT      13

typedef _Float16 f16x8  __attribute__((ext_vector_type(8)));
typedef float    f32x4  __attribute__((ext_vector_type(4)));
typedef float    f32x2  __attribute__((ext_vector_type(2)));

// ---------------- ws layout ----------------
// [0  , 16K) fragB8 : fp8 A-frags of 16*(W0+W2)  [tile 16][kc 2][lane 64] x 8B
// [16K, 48K) fragW3 : f16 A-frags of 16*W3       [tile 16][kc 2][lane 64] x f16x8
// [48K, 80K) fragDt : f16 A-frags of (W1-W2)^T   [tile 16][kc 2][lane 64] x f16x8
// [80K,144K) fragB2 : f16 A-frags of mlp_w1      [tile 16][kc 4][lane 64] x f16x8
__global__ void din_precompute(const float* __restrict__ attn_w1,
                               const float* __restrict__ mlp_w1,
                               uint2* __restrict__ fragB8,
                               _Float16* __restrict__ fragW3,
                               _Float16* __restrict__ fragDt,
                               _Float16* __restrict__ fragB2) {
  const int gid = blockIdx.x * 256 + threadIdx.x;   // [0, 10240)
  if (gid < 2048) {                                 // fragB8: fp8 16*(W0+W2)
    const int i = gid >> 7, rem = gid & 127, kc = rem >> 6, lane = rem & 63;
    const int n = i * 16 + (lane & 15);
    const int kb = kc * 32 + (lane >> 4) * 8;
    float v[8];
    #pragma unroll
    for (int j = 0; j < 8; ++j)
      v[j] = 16.0f * (attn_w1[(kb + j) * HIDDEN + n] + attn_w1[(128 + kb + j) * HIDDEN + n]);
    int lo = __builtin_amdgcn_cvt_pk_fp8_f32(v[0], v[1], 0, false);
    lo     = __builtin_amdgcn_cvt_pk_fp8_f32(v[2], v[3], lo, true);
    int hi = __builtin_amdgcn_cvt_pk_fp8_f32(v[4], v[5], 0, false);
    hi     = __builtin_amdgcn_cvt_pk_fp8_f32(v[6], v[7], hi, true);
    fragB8[gid] = uint2{(unsigned)lo, (unsigned)hi};
  } else if (gid < 4096) {                          // fragW3: f16 16*W3
    const int g = gid - 2048;
    const int i = g >> 7, rem = g & 127, kc = rem >> 6, lane = rem & 63;
    const int n = i * 16 + (lane & 15);
    const int kb = kc * 32 + (lane >> 4) * 8;
    #pragma unroll
    for (int j = 0; j < 8; ++j)
      fragW3[g * 8 + j] = (_Float16)(16.0f * attn_w1[(192 + kb + j) * HIDDEN + n]);
  } else if (gid < 6144) {                          // fragDt: f16 (W1-W2)^T A-frags
    const int g = gid - 4096;
    const int i = g >> 7, rem = g & 127, kc = rem >> 6, lane = rem & 63;
    const int n = i * 16 + (lane & 15);
    const int kb = kc * 32 + (lane >> 4) * 8;
    #pragma unroll
    for (int j = 0; j < 8; ++j)
      fragDt[g * 8 + j] = (_Float16)(attn_w1[(64 + kb + j) * HIDDEN + n]
                                   - attn_w1[(128 + kb + j) * HIDDEN + n]);
  } else {                                          // fragB2: mlp_w1 f16 A-frags
    const int g = gid - 6144;
    const int nt = g >> 8, kc = (g >> 6) & 3, lane = g & 63;
    const int n = nt * 16 + (lane & 15);
    const int kb = kc * 32 + (lane >> 4) * 8;
    #pragma unroll
    for (int j = 0; j < 8; ++j)
      fragB2[g * 8 + j] = (_Float16)mlp_w1[(kb + j) * HIDDEN + n];
  }
}

// ---------------- single fused kernel: one block (512 thr, 8 waves) per row ----------------
__global__ __launch_bounds__(512, 8)
void din_fused_kernel(const int* __restrict__ user_hist,
                      const int* __restrict__ target_item,
                      const float* __restrict__ user_emb,
                      const float* __restrict__ item_emb,
                      const float* __restrict__ attn_b1,
                      const float* __restrict__ attn_w2,
                      const float* __restrict__ mlp_b1,
                      const float* __restrict__ mlp_w2,
                      const float* __restrict__ mlp_b2,
                      const uint2* __restrict__ fragB8,
                      const _Float16* __restrict__ fragW3,
                      const _Float16* __restrict__ fragDt,
                      const _Float16* __restrict__ fragB2,
                      float* __restrict__ out)
{
  __shared__ __align__(16) uint2 Hf8[MT * 2 * 64];    // 13312 B, fp8(16h) B-frags
  __shared__ __align__(16) _Float16 t16[EMBED];       // 128
  __shared__ int   histL[SEQP];                       // 832
  __shared__ float lp[8][SEQP];                       // 6656
  __shared__ float weights[SEQP];                     // 832
  __shared__ __align__(16) _Float16 mi16[EMBED];      // 128
  __shared__ float red[16];                           // 64
  // total ~22 KB

  const int b    = blockIdx.x;
  const int tid  = threadIdx.x;
  const int lane = tid & 63;
  const int wave = tid >> 6;
  const int m    = lane & 15;
  const int quad = lane >> 4;

  // ---- phase 0: target embedding + hist staging ----
  if (tid < EMBED) t16[tid] = (_Float16)item_emb[target_item[b] * EMBED + tid];
  if (tid < SEQP) histL[tid] = (tid < SEQ) ? user_hist[b * SEQ + tid] : 0;

  // static fp8 weight A-frags (global, independent of LDS)
  long long Aw8[2][2];
  #pragma unroll
  for (int i = 0; i < 2; ++i)
    #pragma unroll
    for (int c = 0; c < 2; ++c)
      Aw8[i][c] = __builtin_bit_cast(long long, fragB8[((2 * wave + i) * 2 + c) * 64 + lane]);
  __syncthreads();

  // ---- phase 1: gather h -> fp8 B-frag LDS (uses histL) ----
  for (int slot = tid; slot < MT * 2 * 64; slot += 512) {
    const int ln = slot & 63, kcomb = slot >> 6;
    const int st = kcomb >> 1, kc = kcomb & 1;
    const int s = st * 16 + (ln & 15);
    const int kb = kc * 32 + (ln >> 4) * 8;
    uint2 pv = uint2{0u, 0u};
    if (s < SEQ) {
      const float4* src = reinterpret_cast<const float4*>(&user_emb[histL[s] * EMBED + kb]);
      const float4 x = src[0], y = src[1];
      int lo = __builtin_amdgcn_cvt_pk_fp8_f32(16.f * x.x, 16.f * x.y, 0, false);
      lo     = __builtin_amdgcn_cvt_pk_fp8_f32(16.f * x.z, 16.f * x.w, lo, true);
      int hi = __builtin_amdgcn_cvt_pk_fp8_f32(16.f * y.x, 16.f * y.y, 0, false);
      hi     = __builtin_amdgcn_cvt_pk_fp8_f32(16.f * y.z, 16.f * y.w, hi, true);
      pv = uint2{(unsigned)lo, (unsigned)hi};
    }
    Hf8[slot] = pv;
  }
  __syncthreads();

  // ---- phase 2: t-folded W3 A-frags + c-fold via MFMA (no scalar dot) ----
  const f16x8 tv0 = *reinterpret_cast<const f16x8*>(&t16[quad * 8]);        // t[quad*8+j]
  const f16x8 tv1 = *reinterpret_cast<const f16x8*>(&t16[32 + quad * 8]);   // t[32+quad*8+j]

  long long AwT[2][2];
  #pragma unroll
  for (int i = 0; i < 2; ++i) {
    #pragma unroll
    for (int c = 0; c < 2; ++c) {
      const f16x8 w3v = reinterpret_cast<const f16x8*>(fragW3)[((2 * wave + i) * 2 + c) * 64 + lane];
      const f16x8 p = w3v * (c ? tv1 : tv0);
      int lo = __builtin_amdgcn_cvt_pk_fp8_f32((float)p[0], (float)p[1], 0, false);
      lo     = __builtin_amdgcn_cvt_pk_fp8_f32((float)p[2], (float)p[3], lo, true);
      int hi = __builtin_amdgcn_cvt_pk_fp8_f32((float)p[4], (float)p[5], 0, false);
      hi     = __builtin_amdgcn_cvt_pk_fp8_f32((float)p[6], (float)p[7], hi, true);
      AwT[i][c] = __builtin_bit_cast(long long, uint2{(unsigned)lo, (unsigned)hi});
    }
  }

  // c-fold: c[n] = b1[n] + sum_k t[k] D[k][n]; A = D^T frags, B = broadcast t
  float cn[2][4], w2n[2][4];
  #pragma unroll
  for (int i = 0; i < 2; ++i) {
    const int tile = 2 * wave + i;
    const f16x8 d0 = reinterpret_cast<const f16x8*>(fragDt)[(tile * 2 + 0) * 64 + lane];
    const f16x8 d1 = reinterpret_cast<const f16x8*>(fragDt)[(tile * 2 + 1) * 64 + lane];
    f32x4 acc = {0.f, 0.f, 0.f, 0.f};
    acc = __builtin_amdgcn_mfma_f32_16x16x32_f16(d0, tv0, acc, 0, 0, 0);
    acc = __builtin_amdgcn_mfma_f32_16x16x32_f16(d1, tv1, acc, 0, 0, 0);
    const int nb = tile * 16 + quad * 4;
    const float4 b1v = *reinterpret_cast<const float4*>(&attn_b1[nb]);
    const float4 w2v = *reinterpret_cast<const float4*>(&attn_w2[nb]);
    cn[i][0] = 256.0f * (b1v.x + acc[0]);
    cn[i][1] = 256.0f * (b1v.y + acc[1]);
    cn[i][2] = 256.0f * (b1v.z + acc[2]);
    cn[i][3] = 256.0f * (b1v.w + acc[3]);
    w2n[i][0] = w2v.x * (1.0f / 256.0f);
    w2n[i][1] = w2v.y * (1.0f / 256.0f);
    w2n[i][2] = w2v.z * (1.0f / 256.0f);
    w2n[i][3] = w2v.w * (1.0f / 256.0f);
  }

  // ---- phase 3: fp8 K=128 MFMA GEMM (H^T); wave owns n-tiles 2w, 2w+1 ----
  #pragma unroll 4
  for (int st = 0; st < MT; ++st) {
    const long long b0 = __builtin_bit_cast(long long, Hf8[(st * 2 + 0) * 64 + lane]);
    const long long b1 = __builtin_bit_cast(long long, Hf8[(st * 2 + 1) * 64 + lane]);
    float lg = 0.f;
    #pragma unroll
    for (int i = 0; i < 2; ++i) {
      f32x4 acc = {cn[i][0], cn[i][1], cn[i][2], cn[i][3]};
      acc = __builtin_amdgcn_mfma_f32_16x16x32_fp8_fp8(Aw8[i][0], b0, acc, 0, 0, 0);
      acc = __builtin_amdgcn_mfma_f32_16x16x32_fp8_fp8(Aw8[i][1], b1, acc, 0, 0, 0);
      acc = __builtin_amdgcn_mfma_f32_16x16x32_fp8_fp8(AwT[i][0], b0, acc, 0, 0, 0);
      acc = __builtin_amdgcn_mfma_f32_16x16x32_fp8_fp8(AwT[i][1], b1, acc, 0, 0, 0);
      #pragma unroll
      for (int r = 0; r < 4; ++r)
        lg += fmaxf(acc[r], 0.0f) * w2n[i][r];
    }
    lg += __shfl_xor(lg, 16, 64);
    lg += __shfl_xor(lg, 32, 64);
    if (lane < 16) lp[wave][st * 16 + lane] = lg;
  }
  __syncthreads();

  // ---- phase 4: softmax over SEQ on waves 0-3 only (uniform barriers) ----
  float v = -INFINITY, e = 0.0f;
  if (wave < 4) {
    if (tid < SEQ)
      v = lp[0][tid] + lp[1][tid] + lp[2][tid] + lp[3][tid]
        + lp[4][tid] + lp[5][tid] + lp[6][tid] + lp[7][tid];
    float mx = v;
    #pragma unroll
    for (int off = 32; off; off >>= 1) mx = fmaxf(mx, __shfl_xor(mx, off, 64));
    if (lane == 0) red[wave] = mx;
  }
  __syncthreads();
  if (wave < 4) {
    const float mx = fmaxf(fmaxf(red[0], red[1]), fmaxf(red[2], red[3]));
    e = (tid < SEQ) ? expf(v - mx) : 0.0f;
    float ssum = e;
    #pragma unroll
    for (int off = 32; off; off >>= 1) ssum += __shfl_xor(ssum, off, 64);
    if (lane == 0) red[4 + wave] = ssum;
  }
  __syncthreads();
  if (wave < 4) {
    const float tot = red[4] + red[5] + red[6] + red[7];
    if (tid < SEQP) weights[tid] = (tid < SEQ) ? e / tot : 0.0f;
  }
  __syncthreads();

  // ---- phase 5: weighted interest pooling; wave -> (kc = w&1, st-group = w>>1) ----
  {
    const int kc = wave & 1, g = wave >> 1;
    float pk[8];
    #pragma unroll
    for (int j = 0; j < 8; ++j) pk[j] = 0.f;
    #pragma unroll
    for (int st2 = 0; st2 < 4; ++st2) {
      const int st = g + st2 * 4;
      if (st < MT) {
        const float wt = weights[st * 16 + m];
        const uint2 hv = Hf8[(st * 2 + kc) * 64 + lane];
        const f32x2 f0 = __builtin_amdgcn_cvt_pk_f32_fp8((int)hv.x, false);
        const f32x2 f1 = __builtin_amdgcn_cvt_pk_f32_fp8((int)hv.x, true);
        const f32x2 f2 = __builtin_amdgcn_cvt_pk_f32_fp8((int)hv.y, false);
        const f32x2 f3 = __builtin_amdgcn_cvt_pk_f32_fp8((int)hv.y, true);
        pk[0] += wt * f0.x;  pk[1] += wt * f0.y;
        pk[2] += wt * f1.x;  pk[3] += wt * f1.y;
        pk[4] += wt * f2.x;  pk[5] += wt * f2.y;
        pk[6] += wt * f3.x;  pk[7] += wt * f3.y;
      }
    }
    #pragma unroll
    for (int j = 0; j < 8; ++j) {
      float p = pk[j];
      p += __shfl_xor(p, 1, 64);
      p += __shfl_xor(p, 2, 64);
      p += __shfl_xor(p, 4, 64);
      p += __shfl_xor(p, 8, 64);
      pk[j] = p;
    }
    if (m == 0) {
      #pragma unroll
      for (int j = 0; j < 8; ++j)
        lp[g][kc * 32 + quad * 8 + j] = pk[j];     // lp reused: interest partials
    }
  }
  __syncthreads();
  if (tid < EMBED)
    mi16[tid] = (_Float16)((lp[0][tid] + lp[1][tid] + lp[2][tid] + lp[3][tid]) * 0.0625f);
  __syncthreads();

  // ---- phase 6: prediction head, f16 MFMA, broadcast-B ----
  {
    const f16x8 mb0 = *reinterpret_cast<const f16x8*>(&mi16[quad * 8]);
    const f16x8 mb1 = *reinterpret_cast<const f16x8*>(&mi16[32 + quad * 8]);
    float z = 0.f;
    #pragma unroll
    for (int i = 0; i < 2; ++i) {
      const f16x8* B2 = reinterpret_cast<const f16x8*>(fragB2) + ((2 * wave + i) * 4) * 64 + lane;
      const int nb = (2 * wave + i) * 16 + quad * 4;
      const float4 bb = *reinterpret_cast<const float4*>(&mlp_b1[nb]);
      const float4 ww = *reinterpret_cast<const float4*>(&mlp_w2[nb]);
      f32x4 acc = {bb.x, bb.y, bb.z, bb.w};
      acc = __builtin_amdgcn_mfma_f32_16x16x32_f16(B2[0],   mb0, acc, 0, 0, 0);
      acc = __builtin_amdgcn_mfma_f32_16x16x32_f16(B2[64],  mb1, acc, 0, 0, 0);
      acc = __builtin_amdgcn_mfma_f32_16x16x32_f16(B2[128], tv0, acc, 0, 0, 0);
      acc = __builtin_amdgcn_mfma_f32_16x16x32_f16(B2[192], tv1, acc, 0, 0, 0);
      z += fmaxf(acc[0], 0.0f) * ww.x;
      z += fmaxf(acc[1], 0.0f) * ww.y;
      z += fmaxf(acc[2], 0.0f) * ww.z;
      z += fmaxf(acc[3], 0.0f) * ww.w;
    }
    z += __shfl_xor(z, 16, 64);
    z += __shfl_xor(z, 32, 64);
    if (lane == 0) red[wave] = z;
  }
  __syncthreads();
  if (tid == 0) {
    const float zz = red[0] + red[1] + red[2] + red[3]
                   + red[4] + red[5] + red[6] + red[7] + mlp_b2[0];
    out[b] = 1.0f / (1.0f + expf(-zz));
  }
}

extern "C" void kernel_launch(void* const* d_in, const int* in_sizes, int n_in,
                              void* d_out, int out_size, void* d_ws, size_t ws_size,
                              hipStream_t stream) {
  const int*   user_hist   = (const int*)  d_in[0];
  const int*   target_item = (const int*)  d_in[1];
  const float* user_emb    = (const float*)d_in[2];
  const float* item_emb    = (const float*)d_in[3];
  const float* attn_w1     = (const float*)d_in[4];
  const float* attn_b1     = (const float*)d_in[5];
  const float* attn_w2     = (const float*)d_in[6];
  // d_in[7] = attn_b2: constant shift on logits -> cancels in softmax
  const float* mlp_w1      = (const float*)d_in[8];
  const float* mlp_b1      = (const float*)d_in[9];
  const float* mlp_w2      = (const float*)d_in[10];
  const float* mlp_b2      = (const float*)d_in[11];
  float* out = (float*)d_out;

  uint2*    fragB8 = (uint2*)d_ws;                           // 16 KB
  _Float16* fragW3 = (_Float16*)((char*)d_ws + 16384);       // 32 KB
  _Float16* fragDt = (_Float16*)((char*)d_ws + 49152);       // 32 KB
  _Float16* fragB2 = (_Float16*)((char*)d_ws + 81920);       // 64 KB

  din_precompute<<<40, 256, 0, stream>>>(attn_w1, mlp_w1, fragB8, fragW3, fragDt, fragB2);

  const int batch = in_sizes[1];
  din_fused_kernel<<<batch, 512, 0, stream>>>(
      user_hist, target_item, user_emb, item_emb,
      attn_b1, attn_w2, mlp_b1, mlp_w2, mlp_b2,
      fragB8, fragW3, fragDt, fragB2, out);
}